// Round 2
// baseline (1906.048 us; speedup 1.0000x reference)
//
#include <hip/hip_runtime.h>

#define NR 4096
#define NT 96
#define NNZ_CAP 16384
#define LB 128
#define DHIST 32
#define DTSTEP 3600.0f

// ---------- setup: dense int mask -> CSR ----------

__global__ void mc_count(const int* __restrict__ mask, int* __restrict__ counts) {
  int row = blockIdx.x;
  int lane = threadIdx.x;
  const int* r = mask + (size_t)row * NR;
  int c = 0;
  for (int j = lane; j < NR; j += 64) c += (r[j] != 0);
#pragma unroll
  for (int off = 32; off > 0; off >>= 1) c += __shfl_down(c, off);
  if (lane == 0) counts[row] = c;
}

__global__ __launch_bounds__(1024) void mc_scan(const int* __restrict__ counts,
                                                int* __restrict__ rowptr) {
  __shared__ int s[1024];
  int tid = threadIdx.x;
  int c0 = counts[4 * tid + 0];
  int c1 = counts[4 * tid + 1];
  int c2 = counts[4 * tid + 2];
  int c3 = counts[4 * tid + 3];
  int tot = c0 + c1 + c2 + c3;
  s[tid] = tot;
  __syncthreads();
  for (int off = 1; off < 1024; off <<= 1) {
    int add = (tid >= off) ? s[tid - off] : 0;
    __syncthreads();
    s[tid] += add;
    __syncthreads();
  }
  int base = s[tid] - tot;  // exclusive prefix
  rowptr[4 * tid + 0] = base;
  rowptr[4 * tid + 1] = base + c0;
  rowptr[4 * tid + 2] = base + c0 + c1;
  rowptr[4 * tid + 3] = base + c0 + c1 + c2;
  if (tid == 1023) rowptr[NR] = s[1023];
}

__global__ void mc_fill(const int* __restrict__ mask, const int* __restrict__ rowptr,
                        unsigned short* __restrict__ cols) {
  int row = blockIdx.x;
  int lane = threadIdx.x;
  const int* r = mask + (size_t)row * NR;
  int base = rowptr[row];
  for (int j0 = 0; j0 < NR; j0 += 64) {
    int j = j0 + lane;
    int pred = (r[j] != 0);
    unsigned long long m = __ballot(pred);
    if (pred) {
      int pos = __popcll(m & ((1ull << lane) - 1ull));
      int p = base + pos;
      if (p < NNZ_CAP) cols[p] = (unsigned short)j;
    }
    base += __popcll(m);
  }
}

// ---------- routing: single workgroup, diagonal-pipelined ----------
// Row i at time t = cell (t, l_i). Deps: upstream (t, l<l_i) via global Qhist
// (circular, depth DHIST, agent-scope so L1 can't serve stale), own history
// (t-1,t-2) in registers. One barrier per diagonal s = t + l.

#define ROW_BODY(k, t)                                                         \
  {                                                                            \
    const int i = tid + (k)*1024;                                              \
    float latv = lat[(size_t)(t)*NR + i];                                      \
    float Qref = fmaxf(q1_r[k], 0.1f);                                         \
    float lq = __logf(Qref);                                                   \
    float W = wc_r[k] * __expf(we_r[k] * lq);                                  \
    float Dd = dc_r[k] * __expf(de_r[k] * lq);                                 \
    float R = (W * Dd) / (W + 2.f * Dd);                                       \
    float V = vk_r[k] * __expf(0.66666667f * __logf(fmaxf(R, 1e-6f)));         \
    float c = fmaxf(1.6666667f * V, 0.01f);                                    \
    float K = fmaxf(L_r[k] / c, 0.1f * DTSTEP);                                \
    float X = 0.5f * (1.f - Qref / (W * c * SL_r[k] + 1e-6f));                 \
    X = fminf(fmaxf(X, 0.f), 0.5f);                                            \
    float twoKX = 2.f * K * X;                                                 \
    float C0 = fmaxf(DTSTEP - twoKX, 0.f);                                     \
    float C1 = DTSTEP + twoKX;                                                 \
    float C2 = fmaxf(2.f * K - twoKX - DTSTEP, 0.f);                           \
    float inv = 1.f / (C0 + C1 + C2);                                          \
    const int slot = (t) & (DHIST - 1);                                        \
    float* qrow = Qhist + (size_t)slot * NR;                                   \
    float sup = 0.f;                                                           \
    for (int e = b_r[k]; e < e_r[k]; ++e) {                                    \
      int cj = cols_s[e];                                                      \
      sup += __hip_atomic_load(qrow + cj, __ATOMIC_RELAXED,                    \
                               __HIP_MEMORY_SCOPE_AGENT);                      \
    }                                                                          \
    float Icurr = sup + latv;                                                  \
    float Qout =                                                               \
        fmaxf((C0 * Icurr + C1 * ip_r[k] + C2 * q2_r[k]) * inv, 0.f);          \
    __hip_atomic_store(qrow + i, Qout, __ATOMIC_RELAXED,                       \
                       __HIP_MEMORY_SCOPE_AGENT);                              \
    ip_r[k] = Icurr;                                                           \
    q2_r[k] = q1_r[k];                                                         \
    q1_r[k] = Qout;                                                            \
    if (i == NR - 1) out[t] = Qout;                                            \
  }

__global__ __launch_bounds__(1024) void mc_route(
    const float* __restrict__ lat, const float* __restrict__ initQ,
    const float* __restrict__ Lg, const float* __restrict__ Sg,
    const float* __restrict__ mng, const float* __restrict__ wcg,
    const float* __restrict__ weg, const float* __restrict__ dcg,
    const float* __restrict__ deg, const int* __restrict__ rowptr_g,
    const unsigned short* __restrict__ cols_g, float* Qhist,
    float* __restrict__ out) {
  __shared__ unsigned short cols_s[NNZ_CAP];  // 32 KB
  __shared__ unsigned short level_s[NR];      // 8 KB
  __shared__ int maxLev, flag;

  const int tid = threadIdx.x;
  int nnz = rowptr_g[NR];
  if (nnz > NNZ_CAP) nnz = NNZ_CAP;
  for (int e = tid; e < nnz; e += 1024) cols_s[e] = cols_g[e];

  int b_r[4], e_r[4], lev_r[4];
  float wc_r[4], we_r[4], dc_r[4], de_r[4], vk_r[4], SL_r[4], L_r[4];
  float ip_r[4], q1_r[4], q2_r[4];

#pragma unroll
  for (int k = 0; k < 4; ++k) {
    int i = tid + k * 1024;
    int b = rowptr_g[i], e = rowptr_g[i + 1];
    b_r[k] = b > NNZ_CAP ? NNZ_CAP : b;
    e_r[k] = e > NNZ_CAP ? NNZ_CAP : e;
    level_s[i] = 0;
    float Lv = Lg[i], Sv = Sg[i], mnv = mng[i];
    float sS = fmaxf(Sv, 1e-6f);
    vk_r[k] = sqrtf(sS) / fmaxf(mnv, 1e-3f);
    SL_r[k] = sS * Lv;
    L_r[k] = Lv;
    wc_r[k] = wcg[i];
    we_r[k] = weg[i];
    dc_r[k] = dcg[i];
    de_r[k] = deg[i];
    float q0 = initQ[i];
    q1_r[k] = q0;
    q2_r[k] = q0;
    ip_r[k] = 0.f;
  }
  __syncthreads();

  // iterative longest-path level relaxation (monotone; benign LDS races)
  for (int pass = 0; pass < LB; ++pass) {
    if (tid == 0) flag = 0;
    __syncthreads();
    int ch = 0;
#pragma unroll
    for (int k = 0; k < 4; ++k) {
      int i = tid + k * 1024;
      int lv = 0;
      for (int e = b_r[k]; e < e_r[k]; ++e) {
        int l2 = (int)level_s[cols_s[e]] + 1;
        lv = lv > l2 ? lv : l2;
      }
      if (lv > LB - 1) lv = LB - 1;
      if (lv > (int)level_s[i]) {
        level_s[i] = (unsigned short)lv;
        ch = 1;
      }
    }
    if (ch) flag = 1;
    __syncthreads();
    int done = (flag == 0);
    __syncthreads();
    if (done) break;
  }

  if (tid == 0) maxLev = 0;
  __syncthreads();
  int lm = 0;
#pragma unroll
  for (int k = 0; k < 4; ++k) {
    lev_r[k] = (int)level_s[tid + k * 1024];
    lm = lm > lev_r[k] ? lm : lev_r[k];
  }
  atomicMax(&maxLev, lm);
  __syncthreads();
  const int nlv = maxLev + 1;

  if (nlv <= DHIST) {
    // diagonal-pipelined schedule: one barrier per diagonal
    const int nDiag = NT + nlv - 1;
    for (int s = 0; s < nDiag; ++s) {
#pragma unroll
      for (int k = 0; k < 4; ++k) {
        int t = s - lev_r[k];
        if ((unsigned)t < (unsigned)NT) {
          ROW_BODY(k, t);
        }
      }
      __syncthreads();
    }
  } else {
    // safety fallback: per-timestep level sweep (same body, never expected)
    for (int t = 0; t < NT; ++t) {
      for (int l = 0; l < nlv; ++l) {
#pragma unroll
        for (int k = 0; k < 4; ++k) {
          if (lev_r[k] == l) {
            ROW_BODY(k, t);
          }
        }
        __syncthreads();
      }
    }
  }
}

extern "C" void kernel_launch(void* const* d_in, const int* in_sizes, int n_in,
                              void* d_out, int out_size, void* d_ws, size_t ws_size,
                              hipStream_t stream) {
  const float* lat = (const float*)d_in[0];
  const float* iQ = (const float*)d_in[1];
  const float* Lg = (const float*)d_in[2];
  const float* Sg = (const float*)d_in[3];
  const float* mng = (const float*)d_in[4];
  const float* wcg = (const float*)d_in[5];
  const float* weg = (const float*)d_in[6];
  const float* dcg = (const float*)d_in[7];
  const float* deg = (const float*)d_in[8];
  const int* mask = (const int*)d_in[9];
  float* out = (float*)d_out;

  int* counts = (int*)d_ws;                                   // NR ints
  int* rowptr = counts + NR;                                  // NR+1 ints (+pad)
  unsigned short* cols = (unsigned short*)(rowptr + NR + 4);  // NNZ_CAP u16
  float* Qhist = (float*)(cols + NNZ_CAP);                    // DHIST*NR floats

  mc_count<<<NR, 64, 0, stream>>>(mask, counts);
  mc_scan<<<1, 1024, 0, stream>>>(counts, rowptr);
  mc_fill<<<NR, 64, 0, stream>>>(mask, rowptr, cols);
  mc_route<<<1, 1024, 0, stream>>>(lat, iQ, Lg, Sg, mng, wcg, weg, dcg, deg,
                                   rowptr, cols, Qhist, out);
}

// Round 3
// 1027.521 us; speedup vs baseline: 1.8550x; 1.8550x over previous
//
#include <hip/hip_runtime.h>

#define NR 4096
#define NT 96
#define NNZ_CAP 16384
#define LB 128
#define DHIST 32
#define DTSTEP 3600.0f

// ---------- setup: dense int mask -> CSR (single HBM pass) ----------
// One wave per row. Pass 1: vectorized count (int4). atomicAdd on a global
// cursor gives the row's base (order nondeterministic across rows, but
// within-row column order is always ascending -> output bitwise stable).
// Pass 2 re-reads the row (L2-hot) and ballot-packs column indices.

__global__ void mc_build(const int* __restrict__ mask, int* __restrict__ rowBase,
                         int* __restrict__ rowCnt, int* __restrict__ gctr,
                         unsigned short* __restrict__ cols) {
  int row = blockIdx.x;
  int lane = threadIdx.x;
  const int4* rv = (const int4*)(mask + (size_t)row * NR);
  int c = 0;
  for (int j = lane; j < NR / 4; j += 64) {
    int4 v = rv[j];
    c += (v.x != 0) + (v.y != 0) + (v.z != 0) + (v.w != 0);
  }
#pragma unroll
  for (int off = 32; off > 0; off >>= 1) c += __shfl_down(c, off);
  int base = 0;
  if (lane == 0) {
    base = atomicAdd(gctr, c);
    rowBase[row] = base;
    rowCnt[row] = c;
  }
  base = __shfl(base, 0);

  const int* rs = mask + (size_t)row * NR;
  for (int j0 = 0; j0 < NR; j0 += 64) {
    int j = j0 + lane;
    int pred = (rs[j] != 0);
    unsigned long long m = __ballot(pred);
    if (pred) {
      int pos = __popcll(m & ((1ull << lane) - 1ull));
      int p = base + pos;
      if (p < NNZ_CAP) cols[p] = (unsigned short)j;
    }
    base += __popcll(m);
  }
}

// ---------- routing: single workgroup, diagonal-pipelined ----------
// Row i at time t = cell (t, l_i). Upstream values cross waves through global
// Qhist (circular, depth DHIST) with PLAIN loads/stores: one workgroup = one
// CU = shared L1/L2, and __syncthreads() per diagonal orders/flushes them.
// Own history (Q_{t-1}, Q_{t-2}, I_{t-1}) stays in registers.

#define ROW_BODY(k, t)                                                         \
  {                                                                            \
    const int i = tid + (k)*1024;                                              \
    float latv = lat[(size_t)(t)*NR + i];                                      \
    float Qref = fmaxf(q1_r[k], 0.1f);                                         \
    float lq = __logf(Qref);                                                   \
    float W = wc_r[k] * __expf(we_r[k] * lq);                                  \
    float Dd = dc_r[k] * __expf(de_r[k] * lq);                                 \
    float R = (W * Dd) / (W + 2.f * Dd);                                       \
    float V = vk_r[k] * __expf(0.66666667f * __logf(fmaxf(R, 1e-6f)));         \
    float c = fmaxf(1.6666667f * V, 0.01f);                                    \
    float K = fmaxf(L_r[k] / c, 0.1f * DTSTEP);                                \
    float X = 0.5f * (1.f - Qref / (W * c * SL_r[k] + 1e-6f));                 \
    X = fminf(fmaxf(X, 0.f), 0.5f);                                            \
    float twoKX = 2.f * K * X;                                                 \
    float C0 = fmaxf(DTSTEP - twoKX, 0.f);                                     \
    float C1 = DTSTEP + twoKX;                                                 \
    float C2 = fmaxf(2.f * K - twoKX - DTSTEP, 0.f);                           \
    float inv = 1.f / (C0 + C1 + C2);                                          \
    const int slot = (t) & (DHIST - 1);                                        \
    float* qrow = Qhist + (size_t)slot * NR;                                   \
    float sup = 0.f;                                                           \
    for (int e = b_r[k]; e < e_r[k]; ++e) sup += qrow[cols_s[e]];              \
    float Icurr = sup + latv;                                                  \
    float Qout =                                                               \
        fmaxf((C0 * Icurr + C1 * ip_r[k] + C2 * q2_r[k]) * inv, 0.f);          \
    qrow[i] = Qout;                                                            \
    ip_r[k] = Icurr;                                                           \
    q2_r[k] = q1_r[k];                                                         \
    q1_r[k] = Qout;                                                            \
    if (i == NR - 1) out[t] = Qout;                                            \
  }

__global__ __launch_bounds__(1024) void mc_route(
    const float* __restrict__ lat, const float* __restrict__ initQ,
    const float* __restrict__ Lg, const float* __restrict__ Sg,
    const float* __restrict__ mng, const float* __restrict__ wcg,
    const float* __restrict__ weg, const float* __restrict__ dcg,
    const float* __restrict__ deg, const int* __restrict__ rowBase_g,
    const int* __restrict__ rowCnt_g, const unsigned short* __restrict__ cols_g,
    const int* __restrict__ gctr, float* Qhist, float* __restrict__ out) {
  __shared__ unsigned short cols_s[NNZ_CAP];  // 32 KB
  __shared__ unsigned short level_s[NR];      // 8 KB
  __shared__ int maxLev, flag;

  const int tid = threadIdx.x;
  int nnz = gctr[0];
  if (nnz > NNZ_CAP) nnz = NNZ_CAP;
  for (int e = tid; e < nnz; e += 1024) cols_s[e] = cols_g[e];

  int b_r[4], e_r[4], lev_r[4];
  float wc_r[4], we_r[4], dc_r[4], de_r[4], vk_r[4], SL_r[4], L_r[4];
  float ip_r[4], q1_r[4], q2_r[4];

#pragma unroll
  for (int k = 0; k < 4; ++k) {
    int i = tid + k * 1024;
    int b = rowBase_g[i], e = b + rowCnt_g[i];
    b_r[k] = b > NNZ_CAP ? NNZ_CAP : b;
    e_r[k] = e > NNZ_CAP ? NNZ_CAP : e;
    level_s[i] = 0;
    float Lv = Lg[i], Sv = Sg[i], mnv = mng[i];
    float sS = fmaxf(Sv, 1e-6f);
    vk_r[k] = sqrtf(sS) / fmaxf(mnv, 1e-3f);
    SL_r[k] = sS * Lv;
    L_r[k] = Lv;
    wc_r[k] = wcg[i];
    we_r[k] = weg[i];
    dc_r[k] = dcg[i];
    de_r[k] = deg[i];
    float q0 = initQ[i];
    q1_r[k] = q0;
    q2_r[k] = q0;
    ip_r[k] = 0.f;
  }
  __syncthreads();

  // iterative longest-path level relaxation (monotone; benign LDS races)
  for (int pass = 0; pass < LB; ++pass) {
    if (tid == 0) flag = 0;
    __syncthreads();
    int ch = 0;
#pragma unroll
    for (int k = 0; k < 4; ++k) {
      int i = tid + k * 1024;
      int lv = 0;
      for (int e = b_r[k]; e < e_r[k]; ++e) {
        int l2 = (int)level_s[cols_s[e]] + 1;
        lv = lv > l2 ? lv : l2;
      }
      if (lv > LB - 1) lv = LB - 1;
      if (lv > (int)level_s[i]) {
        level_s[i] = (unsigned short)lv;
        ch = 1;
      }
    }
    if (ch) flag = 1;
    __syncthreads();
    int done = (flag == 0);
    __syncthreads();
    if (done) break;
  }

  if (tid == 0) maxLev = 0;
  __syncthreads();
  int lm = 0;
#pragma unroll
  for (int k = 0; k < 4; ++k) {
    lev_r[k] = (int)level_s[tid + k * 1024];
    lm = lm > lev_r[k] ? lm : lev_r[k];
  }
  atomicMax(&maxLev, lm);
  __syncthreads();
  const int nlv = maxLev + 1;

  if (nlv <= DHIST) {
    // diagonal-pipelined schedule: one barrier per diagonal s = t + level
    const int nDiag = NT + nlv - 1;
    for (int s = 0; s < nDiag; ++s) {
#pragma unroll
      for (int k = 0; k < 4; ++k) {
        int t = s - lev_r[k];
        if ((unsigned)t < (unsigned)NT) {
          ROW_BODY(k, t);
        }
      }
      __syncthreads();
    }
  } else {
    // safety fallback: per-timestep level sweep (same body, never expected)
    for (int t = 0; t < NT; ++t) {
      for (int l = 0; l < nlv; ++l) {
#pragma unroll
        for (int k = 0; k < 4; ++k) {
          if (lev_r[k] == l) {
            ROW_BODY(k, t);
          }
        }
        __syncthreads();
      }
    }
  }
}

extern "C" void kernel_launch(void* const* d_in, const int* in_sizes, int n_in,
                              void* d_out, int out_size, void* d_ws, size_t ws_size,
                              hipStream_t stream) {
  const float* lat = (const float*)d_in[0];
  const float* iQ = (const float*)d_in[1];
  const float* Lg = (const float*)d_in[2];
  const float* Sg = (const float*)d_in[3];
  const float* mng = (const float*)d_in[4];
  const float* wcg = (const float*)d_in[5];
  const float* weg = (const float*)d_in[6];
  const float* dcg = (const float*)d_in[7];
  const float* deg = (const float*)d_in[8];
  const int* mask = (const int*)d_in[9];
  float* out = (float*)d_out;

  int* rowBase = (int*)d_ws;                                  // NR ints
  int* rowCnt = rowBase + NR;                                 // NR ints
  int* gctr = rowCnt + NR;                                    // 1 int (+pad 4)
  unsigned short* cols = (unsigned short*)(gctr + 4);         // NNZ_CAP u16
  float* Qhist = (float*)(cols + NNZ_CAP);                    // DHIST*NR floats

  hipMemsetAsync(gctr, 0, sizeof(int), stream);
  mc_build<<<NR, 64, 0, stream>>>(mask, rowBase, rowCnt, gctr, cols);
  mc_route<<<1, 1024, 0, stream>>>(lat, iQ, Lg, Sg, mng, wcg, weg, dcg, deg,
                                   rowBase, rowCnt, cols, gctr, Qhist, out);
}

// Round 4
// 690.210 us; speedup vs baseline: 2.7615x; 1.4887x over previous
//
#include <hip/hip_runtime.h>

#define NR 4096
#define NT 96
#define NNZ_CAP 10240
#define WLDS 8
#define DHIST 32
#define DTSTEP 3600.0f

// ---------- K1: dense int mask -> CSR (old ids), single HBM pass ----------
__global__ void mc_build(const int* __restrict__ mask, int* __restrict__ rowBase,
                         int* __restrict__ rowCnt, int* __restrict__ gctr,
                         unsigned short* __restrict__ cols) {
  int row = blockIdx.x;
  int lane = threadIdx.x;
  const int4* rv = (const int4*)(mask + (size_t)row * NR);
  int c = 0;
  for (int j = lane; j < NR / 4; j += 64) {
    int4 v = rv[j];
    c += (v.x != 0) + (v.y != 0) + (v.z != 0) + (v.w != 0);
  }
#pragma unroll
  for (int off = 32; off > 0; off >>= 1) c += __shfl_down(c, off);
  int base = 0;
  if (lane == 0) {
    base = atomicAdd(gctr, c);
    rowBase[row] = base;
    rowCnt[row] = c;
  }
  base = __shfl(base, 0);
  const int* rs = mask + (size_t)row * NR;
  for (int j0 = 0; j0 < NR; j0 += 64) {
    int j = j0 + lane;
    int pred = (rs[j] != 0);
    unsigned long long m = __ballot(pred);
    if (pred) {
      int pos = __popcll(m & ((1ull << lane) - 1ull));
      int p = base + pos;
      if (p < NNZ_CAP) cols[p] = (unsigned short)j;
    }
    base += __popcll(m);
  }
}

// ---------- K2: levels, (level,degree) counting sort, translated CSR ----------
__global__ __launch_bounds__(1024) void mc_prep(
    const int* __restrict__ rowBase, const int* __restrict__ rowCnt,
    const int* __restrict__ gctr, const unsigned short* __restrict__ colsOld,
    unsigned short* __restrict__ orderG, unsigned short* __restrict__ levNG,
    int* __restrict__ rowptrN, unsigned short* __restrict__ colsT,
    int* __restrict__ meta) {
  __shared__ unsigned short cols_s[NNZ_CAP];
  __shared__ unsigned char lev_s[NR];
  __shared__ unsigned short newid_s[NR];
  __shared__ unsigned short order_s[NR];
  __shared__ int cnt[1024];
  __shared__ int sbuf[1024];
  __shared__ int maxLevS, flagS;
  const int tid = threadIdx.x;
  int nnz = gctr[0];
  if (nnz > NNZ_CAP) nnz = NNZ_CAP;
  for (int e = tid; e < nnz; e += 1024) cols_s[e] = colsOld[e];

  int b_r[4], e_r[4];
#pragma unroll
  for (int k = 0; k < 4; ++k) {
    int i = 4 * tid + k;
    int b = rowBase[i];
    if (b > NNZ_CAP) b = NNZ_CAP;
    int e = b + rowCnt[i];
    if (e > NNZ_CAP) e = NNZ_CAP;
    b_r[k] = b;
    e_r[k] = e;
    lev_s[i] = 0;
  }
  if (tid == 0) maxLevS = 0;
  __syncthreads();

  // longest-path level relaxation (acyclic: cols strictly < row)
  for (int pass = 0; pass < 48; ++pass) {
    if (tid == 0) flagS = 0;
    __syncthreads();
    int ch = 0;
#pragma unroll
    for (int k = 0; k < 4; ++k) {
      int i = 4 * tid + k;
      int lv = 0;
      for (int e = b_r[k]; e < e_r[k]; ++e) {
        int l2 = (int)lev_s[cols_s[e]] + 1;
        lv = lv > l2 ? lv : l2;
      }
      if (lv > 127) lv = 127;
      if (lv > (int)lev_s[i]) {
        lev_s[i] = (unsigned char)lv;
        ch = 1;
      }
    }
    if (ch) flagS = 1;
    __syncthreads();
    int done = (flagS == 0);
    __syncthreads();
    if (done) break;
  }
  int lm = 0;
#pragma unroll
  for (int k = 0; k < 4; ++k) {
    int l = lev_s[4 * tid + k];
    lm = lm > l ? lm : l;
  }
  atomicMax(&maxLevS, lm);
  __syncthreads();
  const int maxLev = maxLevS;
  if (tid == 0) {
    meta[0] = maxLev + 1;
    meta[2] = (maxLev >= DHIST) ? 1 : 0;
  }
  if (maxLev >= DHIST) {  // fallback: identity order, route uses old CSR
#pragma unroll
    for (int k = 0; k < 4; ++k) {
      int i = 4 * tid + k;
      orderG[i] = (unsigned short)i;
      levNG[i] = (unsigned short)lev_s[i];
    }
    return;
  }

  // counting sort by bucket = lev*32 + min(deg,31)
  cnt[tid] = 0;
  __syncthreads();
  int bkt_r[4];
#pragma unroll
  for (int k = 0; k < 4; ++k) {
    int i = 4 * tid + k;
    int d = e_r[k] - b_r[k];
    if (d > 31) d = 31;
    int bkt = ((int)lev_s[i]) * 32 + d;
    bkt_r[k] = bkt;
    atomicAdd(&cnt[bkt], 1);
  }
  __syncthreads();
  int v = cnt[tid];
  sbuf[tid] = v;
  __syncthreads();
  for (int off = 1; off < 1024; off <<= 1) {
    int add = tid >= off ? sbuf[tid - off] : 0;
    __syncthreads();
    sbuf[tid] += add;
    __syncthreads();
  }
  cnt[tid] = sbuf[tid] - v;  // exclusive start -> cursor
  __syncthreads();
#pragma unroll
  for (int k = 0; k < 4; ++k) {
    int i = 4 * tid + k;
    int pos = atomicAdd(&cnt[bkt_r[k]], 1);
    order_s[pos] = (unsigned short)i;
    newid_s[i] = (unsigned short)pos;
  }
  __syncthreads();

  // new-order CSR (rowptrN, colsT with lag flag in bit 15)
  int ob_r[4], c_r[4], tot = 0;
  unsigned char lvp_r[4];
#pragma unroll
  for (int k = 0; k < 4; ++k) {
    int p = 4 * tid + k;
    int oldi = order_s[p];
    orderG[p] = (unsigned short)oldi;
    unsigned char lp = lev_s[oldi];
    lvp_r[k] = lp;
    levNG[p] = (unsigned short)lp;
    int b = rowBase[oldi];
    if (b > NNZ_CAP) b = NNZ_CAP;
    int e = b + rowCnt[oldi];
    if (e > NNZ_CAP) e = NNZ_CAP;
    ob_r[k] = b;
    c_r[k] = e - b;
    tot += c_r[k];
  }
  sbuf[tid] = tot;
  __syncthreads();
  for (int off = 1; off < 1024; off <<= 1) {
    int add = tid >= off ? sbuf[tid - off] : 0;
    __syncthreads();
    sbuf[tid] += add;
    __syncthreads();
  }
  int base = sbuf[tid] - tot;
#pragma unroll
  for (int k = 0; k < 4; ++k) {
    int p = 4 * tid + k;
    rowptrN[p] = base;
    for (int e = 0; e < c_r[k]; ++e) {
      int cOld = cols_s[ob_r[k] + e];
      int cN = newid_s[cOld];
      int lag = (int)lvp_r[k] - (int)lev_s[cOld];
      int idx = base + e;
      if (idx < NNZ_CAP)
        colsT[idx] = (unsigned short)(cN | (lag >= WLDS ? 0x8000 : 0));
    }
    base += c_r[k];
  }
  if (tid == 1023) rowptrN[NR] = sbuf[1023];
  if (tid == 0) meta[1] = newid_s[NR - 1];
}

// ---------- K3: permute lateral inflows into sorted order ----------
__global__ void mc_permlat(const float* __restrict__ lat,
                           const unsigned short* __restrict__ orderG,
                           float* __restrict__ latP) {
  int g = blockIdx.x * 256 + threadIdx.x;  // NT*NR threads
  int t = g >> 12, p = g & 4095;
  latP[g] = lat[t * NR + orderG[p]];
}

// ---------- K4: diagonal-pipelined route, LDS window + rare global ----------
__device__ __forceinline__ void mc_coeff(float q1, float wc, float we, float dc,
                                         float de, float vk, float SL, float Lv,
                                         float& C0, float& C1, float& C2,
                                         float& inv) {
  float Qref = fmaxf(q1, 0.1f);
  float lq = __logf(Qref);
  float W = wc * __expf(we * lq);
  float Dd = dc * __expf(de * lq);
  float R = (W * Dd) / (W + 2.f * Dd);
  float V = vk * __expf(0.66666667f * __logf(fmaxf(R, 1e-6f)));
  float c = fmaxf(1.6666667f * V, 0.01f);
  float K = fmaxf(Lv / c, 0.1f * DTSTEP);
  float X = 0.5f * (1.f - Qref / (W * c * SL + 1e-6f));
  X = fminf(fmaxf(X, 0.f), 0.5f);
  float twoKX = 2.f * K * X;
  C0 = fmaxf(DTSTEP - twoKX, 0.f);
  C1 = DTSTEP + twoKX;
  C2 = fmaxf(2.f * K - twoKX - DTSTEP, 0.f);
  inv = 1.f / (C0 + C1 + C2);
}

__global__ __launch_bounds__(1024) void mc_route(
    const float* __restrict__ lat, const float* __restrict__ latP,
    const float* __restrict__ initQ, const float* __restrict__ Lg,
    const float* __restrict__ Sg, const float* __restrict__ mng,
    const float* __restrict__ wcg, const float* __restrict__ weg,
    const float* __restrict__ dcg, const float* __restrict__ deg,
    const int* __restrict__ rowBase, const int* __restrict__ rowCnt,
    const unsigned short* __restrict__ colsOld,
    const unsigned short* __restrict__ orderG,
    const unsigned short* __restrict__ levNG, const int* __restrict__ rowptrN,
    const unsigned short* __restrict__ colsT, const int* __restrict__ meta,
    float* Qhist, float* __restrict__ out, int usePerm) {
  __shared__ float win[WLDS * NR];             // 131072 B
  __shared__ unsigned short cols_s[NNZ_CAP];   // 20480 B
  const int tid = threadIdx.x;
  const int nlv = meta[0];
  const int fb = meta[2];
  const int outletNew = meta[1];

  int b_r[4], e_r[4], lev_r[4], oldi_r[4];
  float wc_r[4], we_r[4], dc_r[4], de_r[4], vk_r[4], SL_r[4], L_r[4];
  float ip_r[4], q1_r[4], q2_r[4];

  if (!fb) {
    int nnzN = rowptrN[NR];
    if (nnzN > NNZ_CAP) nnzN = NNZ_CAP;
    for (int e = tid; e < nnzN; e += 1024) cols_s[e] = colsT[e];
#pragma unroll
    for (int k = 0; k < 4; ++k) {
      int p = tid + k * 1024;
      int oldi = orderG[p];
      oldi_r[k] = oldi;
      lev_r[k] = (int)levNG[p];
      int b = rowptrN[p];
      if (b > NNZ_CAP) b = NNZ_CAP;
      int e = rowptrN[p + 1];
      if (e > NNZ_CAP) e = NNZ_CAP;
      b_r[k] = b;
      e_r[k] = e;
      float Lv = Lg[oldi], Sv = Sg[oldi], mnv = mng[oldi];
      float sS = fmaxf(Sv, 1e-6f);
      vk_r[k] = sqrtf(sS) / fmaxf(mnv, 1e-3f);
      SL_r[k] = sS * Lv;
      L_r[k] = Lv;
      wc_r[k] = wcg[oldi];
      we_r[k] = weg[oldi];
      dc_r[k] = dcg[oldi];
      de_r[k] = deg[oldi];
      float q0 = initQ[oldi];
      q1_r[k] = q0;
      q2_r[k] = q0;
      ip_r[k] = 0.f;
    }
    __syncthreads();

    const int nDiag = NT + nlv - 1;
    for (int s = 0; s < nDiag; ++s) {
#pragma unroll
      for (int k = 0; k < 4; ++k) {
        int t = s - lev_r[k];
        if ((unsigned)t < (unsigned)NT) {
          int p = tid + k * 1024;
          float latv = usePerm ? latP[t * NR + p] : lat[t * NR + oldi_r[k]];
          float C0, C1, C2, inv;
          mc_coeff(q1_r[k], wc_r[k], we_r[k], dc_r[k], de_r[k], vk_r[k],
                   SL_r[k], L_r[k], C0, C1, C2, inv);
          float sup = 0.f;
          for (int e = b_r[k]; e < e_r[k]; ++e) {
            int c = cols_s[e];
            float v;
            if (c & 0x8000)
              v = Qhist[((t & (DHIST - 1)) << 12) | (c & 0x0FFF)];
            else
              v = win[((t & (WLDS - 1)) << 12) | c];
            sup += v;
          }
          float Icurr = sup + latv;
          float Qout =
              fmaxf((C0 * Icurr + C1 * ip_r[k] + C2 * q2_r[k]) * inv, 0.f);
          win[((t & (WLDS - 1)) << 12) | p] = Qout;
          Qhist[((t & (DHIST - 1)) << 12) | p] = Qout;
          ip_r[k] = Icurr;
          q2_r[k] = q1_r[k];
          q1_r[k] = Qout;
          if (p == outletNew) out[t] = Qout;
        }
      }
      __syncthreads();
    }
  } else {
    // safety fallback (nlv > DHIST, statistically impossible): per-t level sweep
    int nnz = 0;  // use old CSR
    (void)nnz;
    for (int e = tid; e < NNZ_CAP; e += 1024) cols_s[e] = colsOld[e];
#pragma unroll
    for (int k = 0; k < 4; ++k) {
      int i = tid + k * 1024;
      oldi_r[k] = i;
      lev_r[k] = (int)levNG[i];
      int b = rowBase[i];
      if (b > NNZ_CAP) b = NNZ_CAP;
      int e = b + rowCnt[i];
      if (e > NNZ_CAP) e = NNZ_CAP;
      b_r[k] = b;
      e_r[k] = e;
      float Lv = Lg[i], Sv = Sg[i], mnv = mng[i];
      float sS = fmaxf(Sv, 1e-6f);
      vk_r[k] = sqrtf(sS) / fmaxf(mnv, 1e-3f);
      SL_r[k] = sS * Lv;
      L_r[k] = Lv;
      wc_r[k] = wcg[i];
      we_r[k] = weg[i];
      dc_r[k] = dcg[i];
      de_r[k] = deg[i];
      float q0 = initQ[i];
      q1_r[k] = q0;
      q2_r[k] = q0;
      ip_r[k] = 0.f;
    }
    __syncthreads();
    for (int t = 0; t < NT; ++t) {
      for (int l = 0; l < nlv; ++l) {
#pragma unroll
        for (int k = 0; k < 4; ++k) {
          if (lev_r[k] == l) {
            int i = tid + k * 1024;
            float latv = lat[t * NR + i];
            float C0, C1, C2, inv;
            mc_coeff(q1_r[k], wc_r[k], we_r[k], dc_r[k], de_r[k], vk_r[k],
                     SL_r[k], L_r[k], C0, C1, C2, inv);
            float sup = 0.f;
            for (int e = b_r[k]; e < e_r[k]; ++e) sup += Qhist[cols_s[e]];
            float Icurr = sup + latv;
            float Qout =
                fmaxf((C0 * Icurr + C1 * ip_r[k] + C2 * q2_r[k]) * inv, 0.f);
            Qhist[i] = Qout;
            ip_r[k] = Icurr;
            q2_r[k] = q1_r[k];
            q1_r[k] = Qout;
            if (i == NR - 1) out[t] = Qout;
          }
        }
        __syncthreads();
      }
    }
  }
}

extern "C" void kernel_launch(void* const* d_in, const int* in_sizes, int n_in,
                              void* d_out, int out_size, void* d_ws, size_t ws_size,
                              hipStream_t stream) {
  const float* lat = (const float*)d_in[0];
  const float* iQ = (const float*)d_in[1];
  const float* Lg = (const float*)d_in[2];
  const float* Sg = (const float*)d_in[3];
  const float* mng = (const float*)d_in[4];
  const float* wcg = (const float*)d_in[5];
  const float* weg = (const float*)d_in[6];
  const float* dcg = (const float*)d_in[7];
  const float* deg = (const float*)d_in[8];
  const int* mask = (const int*)d_in[9];
  float* out = (float*)d_out;

  char* w = (char*)d_ws;
  int* rowBase = (int*)w;                w += NR * 4;
  int* rowCnt = (int*)w;                 w += NR * 4;
  int* gctr = (int*)w;                   w += 16;
  int* meta = (int*)w;                   w += 16;
  unsigned short* colsOld = (unsigned short*)w;  w += NNZ_CAP * 2;
  unsigned short* orderG = (unsigned short*)w;   w += NR * 2;
  unsigned short* levNG = (unsigned short*)w;    w += NR * 2;
  int* rowptrN = (int*)w;                w += (NR + 4) * 4;
  unsigned short* colsT = (unsigned short*)w;    w += NNZ_CAP * 2;
  float* Qhist = (float*)w;              w += (size_t)DHIST * NR * 4;
  float* latP = (float*)w;               w += (size_t)NT * NR * 4;
  size_t need = (size_t)(w - (char*)d_ws);
  int usePerm = (ws_size >= need) ? 1 : 0;

  hipMemsetAsync(gctr, 0, sizeof(int), stream);
  mc_build<<<NR, 64, 0, stream>>>(mask, rowBase, rowCnt, gctr, colsOld);
  mc_prep<<<1, 1024, 0, stream>>>(rowBase, rowCnt, gctr, colsOld, orderG, levNG,
                                  rowptrN, colsT, meta);
  if (usePerm)
    mc_permlat<<<(NT * NR) / 256, 256, 0, stream>>>(lat, orderG, latP);
  mc_route<<<1, 1024, 0, stream>>>(lat, latP, iQ, Lg, Sg, mng, wcg, weg, dcg,
                                   deg, rowBase, rowCnt, colsOld, orderG, levNG,
                                   rowptrN, colsT, meta, Qhist, out, usePerm);
}

// Round 5
// 563.516 us; speedup vs baseline: 3.3824x; 1.2248x over previous
//
#include <hip/hip_runtime.h>

#define NR 4096
#define NT 96
#define NNZ_CAP 10240
#define WLDS 8
#define DHIST 32
#define DTSTEP 3600.0f

__device__ __forceinline__ float RCP(float x) { return __builtin_amdgcn_rcpf(x); }

// ---------- K1: dense int mask -> CSR (old ids), single HBM pass ----------
__global__ void mc_build(const int* __restrict__ mask, int* __restrict__ rowBase,
                         int* __restrict__ rowCnt, int* __restrict__ gctr,
                         unsigned short* __restrict__ cols) {
  int row = blockIdx.x;
  int lane = threadIdx.x;
  const int4* rv = (const int4*)(mask + (size_t)row * NR);
  int c = 0;
  for (int j = lane; j < NR / 4; j += 64) {
    int4 v = rv[j];
    c += (v.x != 0) + (v.y != 0) + (v.z != 0) + (v.w != 0);
  }
#pragma unroll
  for (int off = 32; off > 0; off >>= 1) c += __shfl_down(c, off);
  int base = 0;
  if (lane == 0) {
    base = atomicAdd(gctr, c);
    rowBase[row] = base;
    rowCnt[row] = c;
  }
  base = __shfl(base, 0);
  const int* rs = mask + (size_t)row * NR;
  for (int j0 = 0; j0 < NR; j0 += 64) {
    int j = j0 + lane;
    int pred = (rs[j] != 0);
    unsigned long long m = __ballot(pred);
    if (pred) {
      int pos = __popcll(m & ((1ull << lane) - 1ull));
      int p = base + pos;
      if (p < NNZ_CAP) cols[p] = (unsigned short)j;
    }
    base += __popcll(m);
  }
}

// ---------- K2: levels, (level,degree) sort, split CSR, long-source flags ----
__global__ __launch_bounds__(1024) void mc_prep(
    const int* __restrict__ rowBase, const int* __restrict__ rowCnt,
    const int* __restrict__ gctr, const unsigned short* __restrict__ colsOld,
    unsigned short* __restrict__ orderG, unsigned short* __restrict__ levNG,
    int* __restrict__ rowptrN, int* __restrict__ splitN,
    unsigned short* __restrict__ colsT, unsigned char* __restrict__ longSrcG,
    int* __restrict__ meta) {
  __shared__ unsigned short cols_s[NNZ_CAP];
  __shared__ unsigned char lev_s[NR];
  __shared__ unsigned short newid_s[NR];
  __shared__ unsigned short order_s[NR];
  __shared__ unsigned char lsrc_s[NR];
  __shared__ int cnt[1024];
  __shared__ int sbuf[1024];
  __shared__ int maxLevS, flagS;
  const int tid = threadIdx.x;
  int nnz = gctr[0];
  if (nnz > NNZ_CAP) nnz = NNZ_CAP;
  for (int e = tid; e < nnz; e += 1024) cols_s[e] = colsOld[e];

  int b_r[4], e_r[4];
#pragma unroll
  for (int k = 0; k < 4; ++k) {
    int i = 4 * tid + k;
    int b = rowBase[i];
    if (b > NNZ_CAP) b = NNZ_CAP;
    int e = b + rowCnt[i];
    if (e > NNZ_CAP) e = NNZ_CAP;
    b_r[k] = b;
    e_r[k] = e;
    lev_s[i] = 0;
    lsrc_s[i] = 0;
  }
  if (tid == 0) maxLevS = 0;
  __syncthreads();

  // longest-path level relaxation (acyclic: cols strictly < row)
  for (int pass = 0; pass < 48; ++pass) {
    if (tid == 0) flagS = 0;
    __syncthreads();
    int ch = 0;
#pragma unroll
    for (int k = 0; k < 4; ++k) {
      int i = 4 * tid + k;
      int lv = 0;
      for (int e = b_r[k]; e < e_r[k]; ++e) {
        int l2 = (int)lev_s[cols_s[e]] + 1;
        lv = lv > l2 ? lv : l2;
      }
      if (lv > 127) lv = 127;
      if (lv > (int)lev_s[i]) {
        lev_s[i] = (unsigned char)lv;
        ch = 1;
      }
    }
    if (ch) flagS = 1;
    __syncthreads();
    int done = (flagS == 0);
    __syncthreads();
    if (done) break;
  }
  int lm = 0;
#pragma unroll
  for (int k = 0; k < 4; ++k) {
    int l = lev_s[4 * tid + k];
    lm = lm > l ? lm : l;
  }
  atomicMax(&maxLevS, lm);
  __syncthreads();
  const int maxLev = maxLevS;
  if (tid == 0) {
    meta[0] = maxLev + 1;
    meta[2] = (maxLev >= DHIST) ? 1 : 0;
  }
  if (maxLev >= DHIST) {  // fallback: identity order, route uses old CSR
#pragma unroll
    for (int k = 0; k < 4; ++k) {
      int i = 4 * tid + k;
      orderG[i] = (unsigned short)i;
      levNG[i] = (unsigned short)lev_s[i];
    }
    return;
  }

  // counting sort by bucket = lev*32 + min(deg,31)
  cnt[tid] = 0;
  __syncthreads();
  int bkt_r[4];
#pragma unroll
  for (int k = 0; k < 4; ++k) {
    int i = 4 * tid + k;
    int d = e_r[k] - b_r[k];
    if (d > 31) d = 31;
    int bkt = ((int)lev_s[i]) * 32 + d;
    bkt_r[k] = bkt;
    atomicAdd(&cnt[bkt], 1);
  }
  __syncthreads();
  int v = cnt[tid];
  sbuf[tid] = v;
  __syncthreads();
  for (int off = 1; off < 1024; off <<= 1) {
    int add = tid >= off ? sbuf[tid - off] : 0;
    __syncthreads();
    sbuf[tid] += add;
    __syncthreads();
  }
  cnt[tid] = sbuf[tid] - v;  // exclusive start -> cursor
  __syncthreads();
#pragma unroll
  for (int k = 0; k < 4; ++k) {
    int i = 4 * tid + k;
    int pos = atomicAdd(&cnt[bkt_r[k]], 1);
    order_s[pos] = (unsigned short)i;
    newid_s[i] = (unsigned short)pos;
  }
  __syncthreads();

  // new-order split CSR: per row [short-lag (<WLDS) edges | long-lag edges]
  int ob_r[4], c_r[4], tot = 0;
  unsigned char lvp_r[4];
#pragma unroll
  for (int k = 0; k < 4; ++k) {
    int p = 4 * tid + k;
    int oldi = order_s[p];
    orderG[p] = (unsigned short)oldi;
    unsigned char lp = lev_s[oldi];
    lvp_r[k] = lp;
    levNG[p] = (unsigned short)lp;
    int b = rowBase[oldi];
    if (b > NNZ_CAP) b = NNZ_CAP;
    int e = b + rowCnt[oldi];
    if (e > NNZ_CAP) e = NNZ_CAP;
    ob_r[k] = b;
    c_r[k] = e - b;
    tot += c_r[k];
  }
  sbuf[tid] = tot;
  __syncthreads();
  for (int off = 1; off < 1024; off <<= 1) {
    int add = tid >= off ? sbuf[tid - off] : 0;
    __syncthreads();
    sbuf[tid] += add;
    __syncthreads();
  }
  int base = sbuf[tid] - tot;
#pragma unroll
  for (int k = 0; k < 4; ++k) {
    int p = 4 * tid + k;
    rowptrN[p] = base;
    int ns = 0;
    for (int e = 0; e < c_r[k]; ++e) {
      int lag = (int)lvp_r[k] - (int)lev_s[cols_s[ob_r[k] + e]];
      ns += (lag < WLDS);
    }
    splitN[p] = base + ns;
    int si = base, li = base + ns;
    for (int e = 0; e < c_r[k]; ++e) {
      int cOld = cols_s[ob_r[k] + e];
      int cN = newid_s[cOld];
      int lag = (int)lvp_r[k] - (int)lev_s[cOld];
      if (lag < WLDS) {
        if (si < NNZ_CAP) colsT[si] = (unsigned short)cN;
        si++;
      } else {
        if (li < NNZ_CAP) colsT[li] = (unsigned short)cN;
        li++;
        lsrc_s[cN] = 1;  // benign race, all write 1
      }
    }
    base += c_r[k];
  }
  if (tid == 1023) rowptrN[NR] = sbuf[1023];
  if (tid == 0) meta[1] = newid_s[NR - 1];
  __syncthreads();
#pragma unroll
  for (int k = 0; k < 4; ++k) {
    int p = 4 * tid + k;
    longSrcG[p] = lsrc_s[p];
  }
}

// ---------- K3: permute lateral inflows into sorted order ----------
__global__ void mc_permlat(const float* __restrict__ lat,
                           const unsigned short* __restrict__ orderG,
                           float* __restrict__ latP) {
  int g = blockIdx.x * 256 + threadIdx.x;  // NT*NR threads
  int t = g >> 12, p = g & 4095;
  latP[g] = lat[t * NR + orderG[p]];
}

// ---------- K4: diagonal-pipelined route ----------
__device__ __forceinline__ void mc_coeff(float q1, float wc, float we, float dc,
                                         float de, float vk, float SL, float Lv,
                                         float& C0, float& C1, float& C2,
                                         float& inv) {
  float Qref = fmaxf(q1, 0.1f);
  float lq = __logf(Qref);
  float W = wc * __expf(we * lq);
  float Dd = dc * __expf(de * lq);
  float R = W * Dd * RCP(W + 2.f * Dd);
  float V = vk * __expf(0.66666667f * __logf(fmaxf(R, 1e-6f)));
  float c = fmaxf(1.6666667f * V, 0.01f);
  float K = fmaxf(Lv * RCP(c), 0.1f * DTSTEP);
  float X = 0.5f - 0.5f * Qref * RCP(W * c * SL + 1e-6f);
  X = fminf(fmaxf(X, 0.f), 0.5f);
  float twoKX = 2.f * K * X;
  C0 = fmaxf(DTSTEP - twoKX, 0.f);
  C1 = DTSTEP + twoKX;
  C2 = fmaxf(2.f * K - twoKX - DTSTEP, 0.f);
  inv = RCP(C0 + C1 + C2);
}

__global__ __launch_bounds__(1024) void mc_route(
    const float* __restrict__ lat, const float* __restrict__ latP,
    const float* __restrict__ initQ, const float* __restrict__ Lg,
    const float* __restrict__ Sg, const float* __restrict__ mng,
    const float* __restrict__ wcg, const float* __restrict__ weg,
    const float* __restrict__ dcg, const float* __restrict__ deg,
    const int* __restrict__ rowBase, const int* __restrict__ rowCnt,
    const unsigned short* __restrict__ colsOld,
    const unsigned short* __restrict__ orderG,
    const unsigned short* __restrict__ levNG, const int* __restrict__ rowptrN,
    const int* __restrict__ splitN, const unsigned short* __restrict__ colsT,
    const unsigned char* __restrict__ longSrcG, const int* __restrict__ meta,
    float* Qhist, float* __restrict__ out, int usePerm) {
  __shared__ float win[WLDS * NR];            // 131072 B
  __shared__ unsigned short cols_s[NNZ_CAP];  // 20480 B
  const int tid = threadIdx.x;
  const int nlv = meta[0];
  const int fb = meta[2];
  const int outletNew = meta[1];

  int b_r[4], m_r[4], e_r[4], lev_r[4], oldi_r[4], io_r[4], ls_r[4];
  float wc_r[4], we_r[4], dc_r[4], de_r[4], vk_r[4], SL_r[4], L_r[4];
  float ip_r[4], q1_r[4], q2_r[4];

  if (!fb) {
    int nnzN = rowptrN[NR];
    if (nnzN > NNZ_CAP) nnzN = NNZ_CAP;
    for (int e = tid; e < nnzN; e += 1024) cols_s[e] = colsT[e];
#pragma unroll
    for (int k = 0; k < 4; ++k) {
      int p = tid + k * 1024;
      int oldi = orderG[p];
      oldi_r[k] = oldi;
      lev_r[k] = (int)levNG[p];
      int b = rowptrN[p];
      if (b > NNZ_CAP) b = NNZ_CAP;
      int m = splitN[p];
      if (m > NNZ_CAP) m = NNZ_CAP;
      int e = rowptrN[p + 1];
      if (e > NNZ_CAP) e = NNZ_CAP;
      b_r[k] = b;
      m_r[k] = m;
      e_r[k] = e;
      io_r[k] = (p == outletNew);
      ls_r[k] = (int)longSrcG[p];
      float Lv = Lg[oldi], Sv = Sg[oldi], mnv = mng[oldi];
      float sS = fmaxf(Sv, 1e-6f);
      vk_r[k] = sqrtf(sS) * RCP(fmaxf(mnv, 1e-3f));
      SL_r[k] = sS * Lv;
      L_r[k] = Lv;
      wc_r[k] = wcg[oldi];
      we_r[k] = weg[oldi];
      dc_r[k] = dcg[oldi];
      de_r[k] = deg[oldi];
      float q0 = initQ[oldi];
      q1_r[k] = q0;
      q2_r[k] = q0;
      ip_r[k] = 0.f;
    }
    __syncthreads();

#define BODY(k, tt)                                                            \
  {                                                                            \
    const int p = tid + (k)*1024;                                              \
    float latv = usePerm ? latP[(tt)*NR + p] : lat[(tt)*NR + oldi_r[k]];       \
    float C0, C1, C2, inv;                                                     \
    mc_coeff(q1_r[k], wc_r[k], we_r[k], dc_r[k], de_r[k], vk_r[k], SL_r[k],    \
             L_r[k], C0, C1, C2, inv);                                         \
    const int wEl = ((tt) & (WLDS - 1)) << 12;                                 \
    float sup = 0.f;                                                           \
    for (int e = b_r[k]; e < m_r[k]; ++e) sup += win[wEl | cols_s[e]];         \
    if (m_r[k] < e_r[k]) {                                                     \
      const float* qb = Qhist + (((tt) & (DHIST - 1)) << 12);                  \
      for (int e = m_r[k]; e < e_r[k]; ++e) sup += qb[cols_s[e]];              \
    }                                                                          \
    float Icurr = sup + latv;                                                  \
    float Qout = fmaxf((C0 * Icurr + C1 * ip_r[k] + C2 * q2_r[k]) * inv, 0.f); \
    win[wEl | p] = Qout;                                                       \
    if (ls_r[k]) Qhist[((((tt) & (DHIST - 1)) << 12)) | p] = Qout;             \
    ip_r[k] = Icurr;                                                           \
    q2_r[k] = q1_r[k];                                                         \
    q1_r[k] = Qout;                                                            \
    if (io_r[k]) out[tt] = Qout;                                               \
  }

#define BODYC(k, s)                                                            \
  {                                                                            \
    int t = (s)-lev_r[k];                                                      \
    if ((unsigned)t < (unsigned)NT) BODY(k, t)                                 \
  }

    // ramp-up
    for (int s = 0; s < nlv - 1; ++s) {
#pragma unroll
      for (int k = 0; k < 4; ++k) BODYC(k, s);
      __syncthreads();
    }
    // steady: every row active, no validity checks
    for (int s = nlv - 1; s < NT; ++s) {
#pragma unroll
      for (int k = 0; k < 4; ++k) {
        int t = s - lev_r[k];
        BODY(k, t);
      }
      __syncthreads();
    }
    // drain
    for (int s = NT; s < NT + nlv - 1; ++s) {
#pragma unroll
      for (int k = 0; k < 4; ++k) BODYC(k, s);
      __syncthreads();
    }
  } else {
    // safety fallback (nlv > DHIST, statistically impossible): per-t level sweep
    for (int e = tid; e < NNZ_CAP; e += 1024) cols_s[e] = colsOld[e];
#pragma unroll
    for (int k = 0; k < 4; ++k) {
      int i = tid + k * 1024;
      lev_r[k] = (int)levNG[i];
      int b = rowBase[i];
      if (b > NNZ_CAP) b = NNZ_CAP;
      int e = b + rowCnt[i];
      if (e > NNZ_CAP) e = NNZ_CAP;
      b_r[k] = b;
      e_r[k] = e;
      float Lv = Lg[i], Sv = Sg[i], mnv = mng[i];
      float sS = fmaxf(Sv, 1e-6f);
      vk_r[k] = sqrtf(sS) * RCP(fmaxf(mnv, 1e-3f));
      SL_r[k] = sS * Lv;
      L_r[k] = Lv;
      wc_r[k] = wcg[i];
      we_r[k] = weg[i];
      dc_r[k] = dcg[i];
      de_r[k] = deg[i];
      float q0 = initQ[i];
      q1_r[k] = q0;
      q2_r[k] = q0;
      ip_r[k] = 0.f;
    }
    __syncthreads();
    for (int t = 0; t < NT; ++t) {
      for (int l = 0; l < meta[0]; ++l) {
#pragma unroll
        for (int k = 0; k < 4; ++k) {
          if (lev_r[k] == l) {
            int i = tid + k * 1024;
            float latv = lat[t * NR + i];
            float C0, C1, C2, inv;
            mc_coeff(q1_r[k], wc_r[k], we_r[k], dc_r[k], de_r[k], vk_r[k],
                     SL_r[k], L_r[k], C0, C1, C2, inv);
            float sup = 0.f;
            for (int e = b_r[k]; e < e_r[k]; ++e) sup += Qhist[cols_s[e]];
            float Icurr = sup + latv;
            float Qout =
                fmaxf((C0 * Icurr + C1 * ip_r[k] + C2 * q2_r[k]) * inv, 0.f);
            Qhist[i] = Qout;
            ip_r[k] = Icurr;
            q2_r[k] = q1_r[k];
            q1_r[k] = Qout;
            if (i == NR - 1) out[t] = Qout;
          }
        }
        __syncthreads();
      }
    }
  }
}

extern "C" void kernel_launch(void* const* d_in, const int* in_sizes, int n_in,
                              void* d_out, int out_size, void* d_ws, size_t ws_size,
                              hipStream_t stream) {
  const float* lat = (const float*)d_in[0];
  const float* iQ = (const float*)d_in[1];
  const float* Lg = (const float*)d_in[2];
  const float* Sg = (const float*)d_in[3];
  const float* mng = (const float*)d_in[4];
  const float* wcg = (const float*)d_in[5];
  const float* weg = (const float*)d_in[6];
  const float* dcg = (const float*)d_in[7];
  const float* deg = (const float*)d_in[8];
  const int* mask = (const int*)d_in[9];
  float* out = (float*)d_out;

  char* w = (char*)d_ws;
  int* rowBase = (int*)w;                w += NR * 4;
  int* rowCnt = (int*)w;                 w += NR * 4;
  int* gctr = (int*)w;                   w += 16;
  int* meta = (int*)w;                   w += 16;
  unsigned short* colsOld = (unsigned short*)w;  w += NNZ_CAP * 2;
  unsigned short* orderG = (unsigned short*)w;   w += NR * 2;
  unsigned short* levNG = (unsigned short*)w;    w += NR * 2;
  int* rowptrN = (int*)w;                w += (NR + 4) * 4;
  int* splitN = (int*)w;                 w += NR * 4;
  unsigned short* colsT = (unsigned short*)w;    w += NNZ_CAP * 2;
  unsigned char* longSrcG = (unsigned char*)w;   w += NR;
  w += 16 - ((size_t)w & 15);
  float* Qhist = (float*)w;              w += (size_t)DHIST * NR * 4;
  float* latP = (float*)w;               w += (size_t)NT * NR * 4;
  size_t need = (size_t)(w - (char*)d_ws);
  int usePerm = (ws_size >= need) ? 1 : 0;

  hipMemsetAsync(gctr, 0, sizeof(int), stream);
  mc_build<<<NR, 64, 0, stream>>>(mask, rowBase, rowCnt, gctr, colsOld);
  mc_prep<<<1, 1024, 0, stream>>>(rowBase, rowCnt, gctr, colsOld, orderG, levNG,
                                  rowptrN, splitN, colsT, longSrcG, meta);
  if (usePerm)
    mc_permlat<<<(NT * NR) / 256, 256, 0, stream>>>(lat, orderG, latP);
  mc_route<<<1, 1024, 0, stream>>>(lat, latP, iQ, Lg, Sg, mng, wcg, weg, dcg,
                                   deg, rowBase, rowCnt, colsOld, orderG, levNG,
                                   rowptrN, splitN, colsT, longSrcG, meta,
                                   Qhist, out, usePerm);
}